// Round 1
// baseline (476.043 us; speedup 1.0000x reference)
//
#include <hip/hip_runtime.h>

// LSSViewTransform: 1x1 conv (context channels only; softmax-mean == 1/64
// identity) + bilinear resize (32,88)->(432,496), half-pixel centers.

#define K_IN    256
#define C_CTX   128
#define C_DEPTH 64
#define H_IN    32
#define W_IN    88
#define POS     (H_IN * W_IN)     // 2816
#define H_OUT   432
#define W_OUT   496
#define XG      (W_OUT / 4)       // 124 float4 groups per output row
#define GPP     (XG * H_OUT)      // 53568 groups per (b,c) plane
#define NPLANE  (4 * C_CTX)       // 512 planes

// ---------------------------------------------------------------------------
// Kernel 1: ctx[b][c][pos] = (sum_i feat[b][i][pos] * Wc[64+c][i] + bc[64+c]) / 64
// Each thread: 4 channels x 4 contiguous positions. W loads are wave-uniform
// (c from blockIdx) -> scalar loads. feat loads are coalesced float4.
// ---------------------------------------------------------------------------
__global__ __launch_bounds__(256) void conv1x1_kernel(
    const float* __restrict__ feat, const float* __restrict__ Wc,
    const float* __restrict__ bc, float* __restrict__ ctx)
{
    int p4 = blockIdx.x * blockDim.x + threadIdx.x;   // float4 group [0, 704)
    if (p4 >= POS / 4) return;
    const int c0 = blockIdx.y * 4;                    // context channel base
    const int b  = blockIdx.z;

    const float* fb = feat + (size_t)b * K_IN * POS + 4 * p4;
    const float* w  = Wc + (size_t)(C_DEPTH + c0) * K_IN;

    float4 a0 = {0.f, 0.f, 0.f, 0.f};
    float4 a1 = {0.f, 0.f, 0.f, 0.f};
    float4 a2 = {0.f, 0.f, 0.f, 0.f};
    float4 a3 = {0.f, 0.f, 0.f, 0.f};

    #pragma unroll 8
    for (int i = 0; i < K_IN; ++i) {
        float4 f = *(const float4*)(fb + (size_t)i * POS);
        float w0 = w[i];
        float w1 = w[K_IN + i];
        float w2 = w[2 * K_IN + i];
        float w3 = w[3 * K_IN + i];
        a0.x = fmaf(f.x, w0, a0.x); a0.y = fmaf(f.y, w0, a0.y);
        a0.z = fmaf(f.z, w0, a0.z); a0.w = fmaf(f.w, w0, a0.w);
        a1.x = fmaf(f.x, w1, a1.x); a1.y = fmaf(f.y, w1, a1.y);
        a1.z = fmaf(f.z, w1, a1.z); a1.w = fmaf(f.w, w1, a1.w);
        a2.x = fmaf(f.x, w2, a2.x); a2.y = fmaf(f.y, w2, a2.y);
        a2.z = fmaf(f.z, w2, a2.z); a2.w = fmaf(f.w, w2, a2.w);
        a3.x = fmaf(f.x, w3, a3.x); a3.y = fmaf(f.y, w3, a3.y);
        a3.z = fmaf(f.z, w3, a3.z); a3.w = fmaf(f.w, w3, a3.w);
    }

    const float s = 1.0f / 64.0f;   // mean(softmax) == 1/64 exactly
    float4 accs[4] = {a0, a1, a2, a3};
    #pragma unroll
    for (int j = 0; j < 4; ++j) {
        float bb = bc[C_DEPTH + c0 + j];
        float4 r;
        r.x = (accs[j].x + bb) * s;
        r.y = (accs[j].y + bb) * s;
        r.z = (accs[j].z + bb) * s;
        r.w = (accs[j].w + bb) * s;
        *(float4*)(ctx + ((size_t)(b * C_CTX + c0 + j) * POS + 4 * p4)) = r;
    }
}

// ---------------------------------------------------------------------------
// Kernel 2: bilinear resize, one thread per float4 of output row.
// src = (i + 0.5) * in/out - 0.5, edge clamp (== jax renormalized triangle).
// 4 consecutive outputs span <= 0.54 input px -> 3 taps/row suffice.
// ---------------------------------------------------------------------------
__global__ __launch_bounds__(256) void resize_kernel(
    const float* __restrict__ ctx, float* __restrict__ out)
{
    int g = blockIdx.x * blockDim.x + threadIdx.x;
    if (g >= GPP) return;
    int y  = g / XG;
    int xg = g - y * XG;
    int plane = blockIdx.y;                 // b*128 + c

    const float* p = ctx + (size_t)plane * POS;

    const float SCY = 32.0f / 432.0f;
    const float SCX = 88.0f / 496.0f;

    float sy = (y + 0.5f) * SCY - 0.5f;
    float fyf = floorf(sy);
    float wy = sy - fyf;
    int y0 = (int)fyf;
    int y0c = max(y0, 0);
    int y1c = min(y0 + 1, H_IN - 1);
    const float* r0 = p + y0c * W_IN;
    const float* r1 = p + y1c * W_IN;

    float sx0 = (4 * xg + 0.5f) * SCX - 0.5f;
    int xb = (int)floorf(sx0);

    float ry[3];
    #pragma unroll
    for (int t = 0; t < 3; ++t) {
        int xt = min(max(xb + t, 0), W_IN - 1);
        float a = r0[xt];
        float b = r1[xt];
        ry[t] = a + wy * (b - a);           // y-interpolated row values
    }

    float o[4];
    #pragma unroll
    for (int j = 0; j < 4; ++j) {
        float s  = (4 * xg + j + 0.5f) * SCX - 0.5f;
        float fs = floorf(s);
        float fx = s - fs;
        int t = (int)fs - xb;               // 0 or 1 (monotone fp, safe)
        o[j] = ry[t] + fx * (ry[t + 1] - ry[t]);
    }

    size_t oidx = ((size_t)plane * H_OUT + y) * W_OUT + 4 * xg;
    float4 v = {o[0], o[1], o[2], o[3]};
    *(float4*)(out + oidx) = v;
}

extern "C" void kernel_launch(void* const* d_in, const int* in_sizes, int n_in,
                              void* d_out, int out_size, void* d_ws, size_t ws_size,
                              hipStream_t stream) {
    const float* feat = (const float*)d_in[0];   // (4, 256, 32, 88)
    const float* Wc   = (const float*)d_in[1];   // (192, 256)
    const float* bc   = (const float*)d_in[2];   // (192,)
    float* out = (float*)d_out;                  // (4, 128, 432, 496)
    float* ctx = (float*)d_ws;                   // (4, 128, 2816) = 5.77 MB

    dim3 b1(256);
    dim3 g1((POS / 4 + 255) / 256, C_CTX / 4, 4);   // (3, 32, 4)
    conv1x1_kernel<<<g1, b1, 0, stream>>>(feat, Wc, bc, ctx);

    dim3 b2(256);
    dim3 g2((GPP + 255) / 256, NPLANE);             // (210, 512)
    resize_kernel<<<g2, b2, 0, stream>>>(ctx, out);
}